// Round 11
// baseline (20.200 us; speedup 1.0000x reference)
//
#include <hip/hip_runtime.h>

#define NQ 10
#define NDEPTH 4
#define NR 16              // amplitudes per lane per element (2^4)

// TWO batch elements per wave (r11): state = 2 x (64 lanes x 16 amps).
// Two fully independent dependency chains interleaved in one instruction
// stream -> DS-shuffle latency of chain A hides under chain B's issue.
// Grid: 1024 waves (1/SIMD), 256 blocks x 256 threads.
// Per-element layout (r7, verified): flat index i = lane*16 + r,
//   qubit q 0..5 -> lane bit (5-q), mask M = 32 >> q; q 6..9 -> reg bit (9-q)
// Exact-math restructuring (verified r7):
//  * ring-0 folded into analytic product init via j(i)=(i^(i>>1))^((i&1)*0x300)
//  * ring-3 removed by pushing Z_q through the CNOTs (parity-mask readout)
// r10: layer loop rolled (I$). Gate impls: DPP xor1/2/8, ds_swizzle xor4/16,
// bpermute xor32 + composed ring permutation.

__device__ __forceinline__ float xf(int i) { return __int_as_float(i); }
__device__ __forceinline__ int   fx(float f) { return __float_as_int(f); }

template<int M>
__device__ __forceinline__ float lane_xor(float v, int addr32) {
    if constexpr (M == 1)        // quad_perm [1,0,3,2]
        return xf(__builtin_amdgcn_update_dpp(fx(v), fx(v), 0xB1, 0xF, 0xF, true));
    else if constexpr (M == 2)   // quad_perm [2,3,0,1]
        return xf(__builtin_amdgcn_update_dpp(fx(v), fx(v), 0x4E, 0xF, 0xF, true));
    else if constexpr (M == 8)   // row_ror:8
        return xf(__builtin_amdgcn_update_dpp(fx(v), fx(v), 0x128, 0xF, 0xF, true));
    else if constexpr (M == 4)   // ds_swizzle bit-mode xor 4
        return xf(__builtin_amdgcn_ds_swizzle(fx(v), 0x101F));
    else if constexpr (M == 16)  // ds_swizzle bit-mode xor 16
        return xf(__builtin_amdgcn_ds_swizzle(fx(v), 0x401F));
    else                         // M == 32: bpermute, addr32 = (lane^32)<<2
        return xf(__builtin_amdgcn_ds_bpermute(addr32, fx(v)));
}

template<int M>
__device__ __forceinline__ void rx_lanebit(float (&re)[2][NR], float (&im)[2][NR],
                                           float c, float s, int addr32) {
    #pragma unroll
    for (int r = 0; r < NR; ++r) {
        #pragma unroll
        for (int e = 0; e < 2; ++e) {
            const float pre = lane_xor<M>(re[e][r], addr32);
            const float pim = lane_xor<M>(im[e][r], addr32);
            re[e][r] = c * re[e][r] + s * pim;
            im[e][r] = c * im[e][r] - s * pre;
        }
    }
}

template<int J>
__device__ __forceinline__ void rx_regbit(float (&re)[2][NR], float (&im)[2][NR],
                                          float c, float s) {
    #pragma unroll
    for (int r0 = 0; r0 < NR; ++r0) {
        if (r0 & (1 << J)) continue;
        const int r1 = r0 | (1 << J);
        #pragma unroll
        for (int e = 0; e < 2; ++e) {
            const float R0 = re[e][r0], M0 = im[e][r0];
            const float R1 = re[e][r1], M1 = im[e][r1];
            re[e][r0] = c * R0 + s * M1;
            im[e][r0] = c * M0 - s * R1;
            re[e][r1] = c * R1 + s * M0;
            im[e][r1] = c * M1 - s * R0;
        }
    }
}

__device__ __forceinline__ void cnot_ring(float (&re)[2][NR], float (&im)[2][NR],
                                          int lane, int jaddr, int addr32) {
    // CNOTs (0->1)...(4->5): composed lane permutation, one bpermute pass
    #pragma unroll
    for (int r = 0; r < NR; ++r) {
        #pragma unroll
        for (int e = 0; e < 2; ++e) {
            re[e][r] = xf(__builtin_amdgcn_ds_bpermute(jaddr, fx(re[e][r])));
            im[e][r] = xf(__builtin_amdgcn_ds_bpermute(jaddr, fx(im[e][r])));
        }
    }
    // C(5->6): ctrl lane bit0, tgt reg bit3 -> conditional reg swap
    const bool ctl = (lane & 1) != 0;
    #pragma unroll
    for (int r = 0; r < 8; ++r) {
        #pragma unroll
        for (int e = 0; e < 2; ++e) {
            const float a0 = re[e][r], a1 = re[e][r + 8];
            re[e][r] = ctl ? a1 : a0;  re[e][r + 8] = ctl ? a0 : a1;
            const float b0 = im[e][r], b1 = im[e][r + 8];
            im[e][r] = ctl ? b1 : b0;  im[e][r + 8] = ctl ? b0 : b1;
        }
    }
    // C(6->7): regs bit3=1 swap bit2
    #pragma unroll
    for (int r = 8; r < 12; ++r) {
        #pragma unroll
        for (int e = 0; e < 2; ++e) {
            float t = re[e][r]; re[e][r] = re[e][r + 4]; re[e][r + 4] = t;
            t = im[e][r]; im[e][r] = im[e][r + 4]; im[e][r + 4] = t;
        }
    }
    // C(7->8): regs bit2=1 swap bit1
    {
        const int rs[4] = {4, 5, 12, 13};
        #pragma unroll
        for (int k = 0; k < 4; ++k) {
            const int r = rs[k];
            #pragma unroll
            for (int e = 0; e < 2; ++e) {
                float t = re[e][r]; re[e][r] = re[e][r + 2]; re[e][r + 2] = t;
                t = im[e][r]; im[e][r] = im[e][r + 2]; im[e][r + 2] = t;
            }
        }
    }
    // C(8->9): regs bit1=1 swap bit0
    {
        const int rs[4] = {2, 6, 10, 14};
        #pragma unroll
        for (int k = 0; k < 4; ++k) {
            const int r = rs[k];
            #pragma unroll
            for (int e = 0; e < 2; ++e) {
                float t = re[e][r]; re[e][r] = re[e][r + 1]; re[e][r + 1] = t;
                t = im[e][r]; im[e][r] = im[e][r + 1]; im[e][r + 1] = t;
            }
        }
    }
    // C(9->0): ctrl reg bit0, tgt lane mask 32 -> bpermute odd regs
    #pragma unroll
    for (int r = 1; r < NR; r += 2) {
        #pragma unroll
        for (int e = 0; e < 2; ++e) {
            re[e][r] = lane_xor<32>(re[e][r], addr32);
            im[e][r] = lane_xor<32>(im[e][r], addr32);
        }
    }
}

__global__ __launch_bounds__(256, 1) void vql_kernel(
    const float* __restrict__ x,     // (B, NQ)
    const float* __restrict__ w,     // (NDEPTH, NQ)
    float* __restrict__ out)         // (B, NQ)
{
    const int lane = threadIdx.x & 63;
    const int b0 = (blockIdx.x * 4 + (threadIdx.x >> 6)) * 2;   // elements b0, b0+1

    const int addr32 = (lane ^ 32) << 2;
    int j = lane;                       // composed C(0->1)..C(4->5) source lane
    j ^= ((j >> 1) & 1);
    j ^= ((j >> 2) & 1) << 1;
    j ^= ((j >> 3) & 1) << 2;
    j ^= ((j >> 4) & 1) << 3;
    j ^= ((j >> 5) & 1) << 4;
    const int jaddr = j << 2;

    // ---- shared layer-0 weight factors ----
    float w0s[NQ], w0c[NQ];
    #pragma unroll
    for (int q = 0; q < NQ; ++q) __sincosf(0.5f * w[q], &w0s[q], &w0c[q]);

    const int L0 = lane & 1,        L1 = (lane >> 1) & 1, L2 = (lane >> 2) & 1;
    const int L3 = (lane >> 3) & 1, L4 = (lane >> 4) & 1, L5 = (lane >> 5) & 1;

    float re[2][NR], im[2][NR];

    // ---- per-element init: product state with ring-0 folded in ----
    #pragma unroll
    for (int e = 0; e < 2; ++e) {
        const float2* xr = reinterpret_cast<const float2*>(x + (b0 + e) * NQ);
        const float2 x01 = xr[0], x23 = xr[1], x45 = xr[2], x67 = xr[3], x89 = xr[4];
        const float xa[NQ] = {0.5f * x01.x, 0.5f * x01.y, 0.5f * x23.x, 0.5f * x23.y,
                              0.5f * x45.x, 0.5f * x45.y, 0.5f * x67.x, 0.5f * x67.y,
                              0.5f * x89.x, 0.5f * x89.y};
        float v0r[NQ], v0i[NQ], v1r[NQ], v1i[NQ];
        #pragma unroll
        for (int q = 0; q < NQ; ++q) {
            float sy, cy;
            __sincosf(xa[q], &sy, &cy);
            v0r[q] = w0c[q] * cy;  v0i[q] = -w0s[q] * sy;
            v1r[q] = w0c[q] * sy;  v1i[q] = -w0s[q] * cy;
        }
        //   q0: L5^r0   q1: L4^L5^r0   q2: L3^L4   q3: L2^L3   q4: L1^L2
        //   q5: L0^L1   q6: r3^L0      q7: r2^r3   q8: r1^r2   q9: r0^r1
        #define FR_(q,bit) ((bit) ? v1r[q] : v0r[q])
        #define FI_(q,bit) ((bit) ? v1i[q] : v0i[q])
        float Plr, Pli;     // f2*f3*f4*f5 (lane-only)
        {
            const int i2 = L3 ^ L4, i3 = L2 ^ L3, i4 = L1 ^ L2, i5 = L0 ^ L1;
            const float t1r = FR_(2,i2) * FR_(3,i3) - FI_(2,i2) * FI_(3,i3);
            const float t1i = FR_(2,i2) * FI_(3,i3) + FI_(2,i2) * FR_(3,i3);
            const float t2r = FR_(4,i4) * FR_(5,i5) - FI_(4,i4) * FI_(5,i5);
            const float t2i = FR_(4,i4) * FI_(5,i5) + FI_(4,i4) * FR_(5,i5);
            Plr = t1r * t2r - t1i * t2i;
            Pli = t1r * t2i + t1i * t2r;
        }
        float Ar[2], Ai[2];  // P_lane * f0(L5^r0) * f1(L4^L5^r0)
        #pragma unroll
        for (int r0 = 0; r0 < 2; ++r0) {
            const int i0 = L5 ^ r0, i1 = L4 ^ L5 ^ r0;
            const float ur = FR_(0,i0) * FR_(1,i1) - FI_(0,i0) * FI_(1,i1);
            const float ui = FR_(0,i0) * FI_(1,i1) + FI_(0,i0) * FR_(1,i1);
            Ar[r0] = Plr * ur - Pli * ui;
            Ai[r0] = Plr * ui + Pli * ur;
        }
        float Dr[2][2], Di[2][2];  // f6(r3^L0) * f7(r2^r3)
        #pragma unroll
        for (int r3 = 0; r3 < 2; ++r3)
            #pragma unroll
            for (int r2 = 0; r2 < 2; ++r2) {
                const int i6 = r3 ^ L0, i7 = r2 ^ r3;
                Dr[r3][r2] = FR_(6,i6) * FR_(7,i7) - FI_(6,i6) * FI_(7,i7);
                Di[r3][r2] = FR_(6,i6) * FI_(7,i7) + FI_(6,i6) * FR_(7,i7);
            }
        float Er[2][2], Ei[2][2];  // f8(a) * f9(bb)
        #pragma unroll
        for (int a = 0; a < 2; ++a)
            #pragma unroll
            for (int bb = 0; bb < 2; ++bb) {
                Er[a][bb] = FR_(8,a) * FR_(9,bb) - FI_(8,a) * FI_(9,bb);
                Ei[a][bb] = FR_(8,a) * FI_(9,bb) + FI_(8,a) * FR_(9,bb);
            }
        #pragma unroll
        for (int r = 0; r < NR; ++r) {
            const int r3 = (r >> 3) & 1, r2 = (r >> 2) & 1, r1 = (r >> 1) & 1, r0 = r & 1;
            const float dr = Dr[r3][r2], di = Di[r3][r2];
            const float er = Er[r1 ^ r2][r0 ^ r1], ei = Ei[r1 ^ r2][r0 ^ r1];
            const float gr = dr * er - di * ei;
            const float gi = dr * ei + di * er;
            re[e][r] = Ar[r0] * gr - Ai[r0] * gi;
            im[e][r] = Ar[r0] * gi + Ai[r0] * gr;
        }
        #undef FR_
        #undef FI_
    }

    // ---- layers 1..3: RX all qubits; ring only after layers 1,2 ----
    #pragma unroll 1
    for (int l = 1; l < NDEPTH; ++l) {
        float c[NQ], s[NQ];
        #pragma unroll
        for (int q = 0; q < NQ; ++q)
            __sincosf(0.5f * w[l * NQ + q], &s[q], &c[q]);
        rx_lanebit<32>(re, im, c[0], s[0], addr32);
        rx_lanebit<16>(re, im, c[1], s[1], addr32);
        rx_lanebit< 8>(re, im, c[2], s[2], addr32);
        rx_lanebit< 4>(re, im, c[3], s[3], addr32);
        rx_lanebit< 2>(re, im, c[4], s[4], addr32);
        rx_lanebit< 1>(re, im, c[5], s[5], addr32);
        rx_regbit<3>(re, im, c[6], s[6]);
        rx_regbit<2>(re, im, c[7], s[7]);
        rx_regbit<1>(re, im, c[8], s[8]);
        rx_regbit<0>(re, im, c[9], s[9]);
        if (l < NDEPTH - 1)
            cnot_ring(re, im, lane, jaddr, addr32);
    }

    // ---- readout: parity-mask observables (ring-3 pushed through) ----
    const float sg1F = (__builtin_popcount(lane & 0x1F) & 1) ? -1.f : 1.f;
    const float sg30 = (__builtin_popcount(lane & 0x30) & 1) ? -1.f : 1.f;
    const float sg38 = (__builtin_popcount(lane & 0x38) & 1) ? -1.f : 1.f;
    const float sg3C = (__builtin_popcount(lane & 0x3C) & 1) ? -1.f : 1.f;
    const float sg3E = (__builtin_popcount(lane & 0x3E) & 1) ? -1.f : 1.f;
    const float sg3F = (__builtin_popcount(lane & 0x3F) & 1) ? -1.f : 1.f;

    float z[2][NQ];
    #pragma unroll
    for (int e = 0; e < 2; ++e) {
        float p[NR];
        #pragma unroll
        for (int r = 0; r < NR; ++r)
            p[r] = re[e][r] * re[e][r] + im[e][r] * im[e][r];
        float S0 = 0.f, S8 = 0.f, SC = 0.f, SE = 0.f, SF = 0.f;
        #pragma unroll
        for (int r = 0; r < NR; ++r) {
            const int b3 = (r >> 3) & 1, b2 = (r >> 2) & 1, b1 = (r >> 1) & 1, b_ = r & 1;
            S0 += p[r];
            S8 += (b3)               ? -p[r] : p[r];
            SC += (b3 ^ b2)          ? -p[r] : p[r];
            SE += (b3 ^ b2 ^ b1)     ? -p[r] : p[r];
            SF += (b3 ^ b2 ^ b1 ^ b_)? -p[r] : p[r];
        }
        z[e][0] = sg1F * SF;
        z[e][1] = sg30 * S0;
        z[e][2] = sg38 * S0;
        z[e][3] = sg3C * S0;
        z[e][4] = sg3E * S0;
        z[e][5] = sg3F * S0;
        z[e][6] = sg3F * S8;
        z[e][7] = sg3F * SC;
        z[e][8] = sg3F * SE;
        z[e][9] = sg3F * SF;
    }

    #pragma unroll
    for (int e = 0; e < 2; ++e)
        #pragma unroll
        for (int q = 0; q < NQ; ++q) {
            z[e][q] += lane_xor<1>(z[e][q], addr32);
            z[e][q] += lane_xor<2>(z[e][q], addr32);
            z[e][q] += lane_xor<4>(z[e][q], addr32);
            z[e][q] += lane_xor<8>(z[e][q], addr32);
            z[e][q] += lane_xor<16>(z[e][q], addr32);
            z[e][q] += lane_xor<32>(z[e][q], addr32);
        }

    if (lane == 0) {
        // 2 rows x 10 floats = 20 contiguous floats, 16B-aligned (b0 even)
        float4* op = reinterpret_cast<float4*>(out + b0 * NQ);
        op[0] = make_float4(z[0][0], z[0][1], z[0][2], z[0][3]);
        op[1] = make_float4(z[0][4], z[0][5], z[0][6], z[0][7]);
        op[2] = make_float4(z[0][8], z[0][9], z[1][0], z[1][1]);
        op[3] = make_float4(z[1][2], z[1][3], z[1][4], z[1][5]);
        op[4] = make_float4(z[1][6], z[1][7], z[1][8], z[1][9]);
    }
}

extern "C" void kernel_launch(void* const* d_in, const int* in_sizes, int n_in,
                              void* d_out, int out_size, void* d_ws, size_t ws_size,
                              hipStream_t stream) {
    const float* x = (const float*)d_in[0];        // (BATCH, NQ) fp32
    const float* w = (const float*)d_in[1];        // (NDEPTH, NQ) fp32
    float* out = (float*)d_out;                    // (BATCH, NQ) fp32
    const int B = in_sizes[0] / NQ;                // 2048
    const int blocks = B / 8;                      // 2 elem/wave, 4 waves/block
    vql_kernel<<<blocks, 256, 0, stream>>>(x, w, out);
}

// Round 12
// 16.676 us; speedup vs baseline: 1.2113x; 1.2113x over previous
//
#include <hip/hip_runtime.h>

#define NQ 10
#define NDEPTH 4
#define NR 16              // amplitudes per lane (2^4)

// One WAVE per batch element: 64 lanes x 16 complex amps = 1024 amplitudes.
// Flat index i = lane*16 + r; index bit k: k>=4 -> lane bit (k-4), k<4 -> reg bit k.
// FULL Clifford restructuring (r12):
//  * ring-0 folded into analytic product init via j(i)=(i^(i>>1))^((i&1)*0x300)  [r7]
//  * rings 1,2 conjugated through the RX layers: ring is GF(2)-linear, so
//    R^-1 X_M R = X_{j(M)} -> layer2 masks = j(M), layer3 masks = j(j(M)).
//    NO ring stages remain in the body.
//  * all three trailing rings (R^3) pushed into readout: Z_q -> Z-string with
//    mask (j^T)^-3(Z_q), verified via j^T(V3(q)) == V2(q) identities.
// Gates: X-string rotation a'[i] = c*a[i] - i*s*a[i^M]; lane part ML via
// DPP (1,2,3,8) / ds_swizzle (any <32) / bpermute (32,40,48); reg part MR free.

__device__ __forceinline__ float xf(int i) { return __int_as_float(i); }
__device__ __forceinline__ int   fx(float f) { return __float_as_int(f); }

template<int ML>
__device__ __forceinline__ float shufML(float v, int a32, int a48, int a40) {
    if constexpr (ML == 1)        // quad_perm [1,0,3,2]
        return xf(__builtin_amdgcn_update_dpp(fx(v), fx(v), 0xB1, 0xF, 0xF, true));
    else if constexpr (ML == 2)   // quad_perm [2,3,0,1]
        return xf(__builtin_amdgcn_update_dpp(fx(v), fx(v), 0x4E, 0xF, 0xF, true));
    else if constexpr (ML == 3)   // quad_perm [3,2,1,0]
        return xf(__builtin_amdgcn_update_dpp(fx(v), fx(v), 0x1B, 0xF, 0xF, true));
    else if constexpr (ML == 8)   // row_ror:8 == xor 8 within 16-lane row
        return xf(__builtin_amdgcn_update_dpp(fx(v), fx(v), 0x128, 0xF, 0xF, true));
    else if constexpr (ML < 32)   // bit-mode xor within 32-lane group
        return xf(__builtin_amdgcn_ds_swizzle(fx(v), (ML << 10) | 0x1F));
    else if constexpr (ML == 32)
        return xf(__builtin_amdgcn_ds_bpermute(a32, fx(v)));
    else if constexpr (ML == 48)
        return xf(__builtin_amdgcn_ds_bpermute(a48, fx(v)));
    else                          // ML == 40
        return xf(__builtin_amdgcn_ds_bpermute(a40, fx(v)));
}

// X-string rotation exp(-i th/2 X_S), index mask M = lane part ML | reg part MR:
//   re'[r] = c*re[r] + s*im_partner ; im'[r] = c*im[r] - s*re_partner
template<int ML, int MR>
__device__ __forceinline__ void xrot(float (&re)[NR], float (&im)[NR],
                                     float c, float s, int a32, int a48, int a40) {
    if constexpr (ML == 0) {
        // pure register pairing
        #pragma unroll
        for (int r = 0; r < NR; ++r) {
            const int r1 = r ^ MR;
            if (r < r1) {
                const float R0 = re[r], M0 = im[r];
                const float R1 = re[r1], M1 = im[r1];
                re[r]  = c * R0 + s * M1;
                im[r]  = c * M0 - s * R1;
                re[r1] = c * R1 + s * M0;
                im[r1] = c * M1 - s * R0;
            }
        }
    } else if constexpr (MR == 0) {
        // lane-only: immediate consume (r10-proven form)
        #pragma unroll
        for (int r = 0; r < NR; ++r) {
            const float pre = shufML<ML>(re[r], a32, a48, a40);
            const float pim = shufML<ML>(im[r], a32, a48, a40);
            re[r] = c * re[r] + s * pim;
            im[r] = c * im[r] - s * pre;
        }
    } else {
        // mixed lane+reg: need temps (consume at r^MR)
        float Sre[NR], Sim[NR];
        #pragma unroll
        for (int r = 0; r < NR; ++r) {
            Sre[r] = shufML<ML>(re[r], a32, a48, a40);
            Sim[r] = shufML<ML>(im[r], a32, a48, a40);
        }
        #pragma unroll
        for (int r = 0; r < NR; ++r) {
            const float nr = c * re[r] + s * Sim[r ^ MR];
            const float ni = c * im[r] - s * Sre[r ^ MR];
            re[r] = nr; im[r] = ni;
        }
    }
}

__global__ __launch_bounds__(256, 2) void vql_kernel(
    const float* __restrict__ x,     // (B, NQ)
    const float* __restrict__ w,     // (NDEPTH, NQ)
    float* __restrict__ out,         // (B, NQ)
    int B)
{
    const int lane = threadIdx.x & 63;
    const int b = blockIdx.x * 4 + (threadIdx.x >> 6);
    if (b >= B) return;

    const int a32 = (lane ^ 32) << 2;
    const int a48 = (lane ^ 48) << 2;
    const int a40 = (lane ^ 40) << 2;

    // ---- per-batch angles (vectorized) ----
    const float2* xr = reinterpret_cast<const float2*>(x + b * NQ);
    const float2 x01 = xr[0], x23 = xr[1], x45 = xr[2], x67 = xr[3], x89 = xr[4];
    const float xa[NQ] = {0.5f * x01.x, 0.5f * x01.y, 0.5f * x23.x, 0.5f * x23.y,
                          0.5f * x45.x, 0.5f * x45.y, 0.5f * x67.x, 0.5f * x67.y,
                          0.5f * x89.x, 0.5f * x89.y};

    // ---- per-qubit factors: RX(w0q) RY(xq) |0> = (v0, v1) ----
    float v0r[NQ], v0i[NQ], v1r[NQ], v1i[NQ];
    #pragma unroll
    for (int q = 0; q < NQ; ++q) {
        float sy, cy, s, c;
        __sincosf(xa[q], &sy, &cy);
        __sincosf(0.5f * w[q], &s, &c);   // layer-0 weights
        v0r[q] = c * cy;  v0i[q] = -s * sy;
        v1r[q] = c * sy;  v1i[q] = -s * cy;
    }

    // ---- init = ring-0 applied to the product state, built DIRECTLY (r7) ----
    //   q0: L5^r0   q1: L4^L5^r0   q2: L3^L4   q3: L2^L3   q4: L1^L2
    //   q5: L0^L1   q6: r3^L0      q7: r2^r3   q8: r1^r2   q9: r0^r1
    const int L0 = lane & 1,        L1 = (lane >> 1) & 1, L2 = (lane >> 2) & 1;
    const int L3 = (lane >> 3) & 1, L4 = (lane >> 4) & 1, L5 = (lane >> 5) & 1;
    #define FR_(q,bit) ((bit) ? v1r[q] : v0r[q])
    #define FI_(q,bit) ((bit) ? v1i[q] : v0i[q])

    float Plr, Pli;     // f2*f3*f4*f5 (lane-only)
    {
        const int i2 = L3 ^ L4, i3 = L2 ^ L3, i4 = L1 ^ L2, i5 = L0 ^ L1;
        const float t1r = FR_(2,i2) * FR_(3,i3) - FI_(2,i2) * FI_(3,i3);
        const float t1i = FR_(2,i2) * FI_(3,i3) + FI_(2,i2) * FR_(3,i3);
        const float t2r = FR_(4,i4) * FR_(5,i5) - FI_(4,i4) * FI_(5,i5);
        const float t2i = FR_(4,i4) * FI_(5,i5) + FI_(4,i4) * FR_(5,i5);
        Plr = t1r * t2r - t1i * t2i;
        Pli = t1r * t2i + t1i * t2r;
    }
    float Ar[2], Ai[2];  // P_lane * f0(L5^r0) * f1(L4^L5^r0)
    #pragma unroll
    for (int r0 = 0; r0 < 2; ++r0) {
        const int i0 = L5 ^ r0, i1 = L4 ^ L5 ^ r0;
        const float ur = FR_(0,i0) * FR_(1,i1) - FI_(0,i0) * FI_(1,i1);
        const float ui = FR_(0,i0) * FI_(1,i1) + FI_(0,i0) * FR_(1,i1);
        Ar[r0] = Plr * ur - Pli * ui;
        Ai[r0] = Plr * ui + Pli * ur;
    }
    float Dr[2][2], Di[2][2];  // f6(r3^L0) * f7(r2^r3)
    #pragma unroll
    for (int r3 = 0; r3 < 2; ++r3)
        #pragma unroll
        for (int r2 = 0; r2 < 2; ++r2) {
            const int i6 = r3 ^ L0, i7 = r2 ^ r3;
            Dr[r3][r2] = FR_(6,i6) * FR_(7,i7) - FI_(6,i6) * FI_(7,i7);
            Di[r3][r2] = FR_(6,i6) * FI_(7,i7) + FI_(6,i6) * FR_(7,i7);
        }
    float Er[2][2], Ei[2][2];  // f8(a) * f9(bb)
    #pragma unroll
    for (int a = 0; a < 2; ++a)
        #pragma unroll
        for (int bb = 0; bb < 2; ++bb) {
            Er[a][bb] = FR_(8,a) * FR_(9,bb) - FI_(8,a) * FI_(9,bb);
            Ei[a][bb] = FR_(8,a) * FI_(9,bb) + FI_(8,a) * FR_(9,bb);
        }
    float re[NR], im[NR];
    #pragma unroll
    for (int r = 0; r < NR; ++r) {
        const int r3 = (r >> 3) & 1, r2 = (r >> 2) & 1, r1 = (r >> 1) & 1, r0 = r & 1;
        const float dr = Dr[r3][r2], di = Di[r3][r2];
        const float er = Er[r1 ^ r2][r0 ^ r1], ei = Ei[r1 ^ r2][r0 ^ r1];
        const float gr = dr * er - di * ei;
        const float gi = dr * ei + di * er;
        re[r] = Ar[r0] * gr - Ai[r0] * gi;
        im[r] = Ar[r0] * gi + Ai[r0] * gr;
    }
    #undef FR_
    #undef FI_

    // ---- layer 1: plain RX masks ----
    {
        float c[NQ], s[NQ];
        #pragma unroll
        for (int q = 0; q < NQ; ++q) __sincosf(0.5f * w[NQ + q], &s[q], &c[q]);
        xrot<32,0>(re, im, c[0], s[0], a32, a48, a40);
        xrot<16,0>(re, im, c[1], s[1], a32, a48, a40);
        xrot< 8,0>(re, im, c[2], s[2], a32, a48, a40);
        xrot< 4,0>(re, im, c[3], s[3], a32, a48, a40);
        xrot< 2,0>(re, im, c[4], s[4], a32, a48, a40);
        xrot< 1,0>(re, im, c[5], s[5], a32, a48, a40);
        xrot<0, 8>(re, im, c[6], s[6], a32, a48, a40);
        xrot<0, 4>(re, im, c[7], s[7], a32, a48, a40);
        xrot<0, 2>(re, im, c[8], s[8], a32, a48, a40);
        xrot<0, 1>(re, im, c[9], s[9], a32, a48, a40);
    }
    // ---- layer 2: masks j(M) ----
    {
        float c[NQ], s[NQ];
        #pragma unroll
        for (int q = 0; q < NQ; ++q) __sincosf(0.5f * w[2 * NQ + q], &s[q], &c[q]);
        xrot<48,0>(re, im, c[0], s[0], a32, a48, a40);
        xrot<24,0>(re, im, c[1], s[1], a32, a48, a40);
        xrot<12,0>(re, im, c[2], s[2], a32, a48, a40);
        xrot< 6,0>(re, im, c[3], s[3], a32, a48, a40);
        xrot< 3,0>(re, im, c[4], s[4], a32, a48, a40);
        xrot< 1,8>(re, im, c[5], s[5], a32, a48, a40);
        xrot<0,12>(re, im, c[6], s[6], a32, a48, a40);
        xrot<0, 6>(re, im, c[7], s[7], a32, a48, a40);
        xrot<0, 3>(re, im, c[8], s[8], a32, a48, a40);
        xrot<48,1>(re, im, c[9], s[9], a32, a48, a40);
    }
    // ---- layer 3: masks j(j(M)) ----
    {
        float c[NQ], s[NQ];
        #pragma unroll
        for (int q = 0; q < NQ; ++q) __sincosf(0.5f * w[3 * NQ + q], &s[q], &c[q]);
        xrot<40,0>(re, im, c[0], s[0], a32, a48, a40);
        xrot<20,0>(re, im, c[1], s[1], a32, a48, a40);
        xrot<10,0>(re, im, c[2], s[2], a32, a48, a40);
        xrot< 5,0>(re, im, c[3], s[3], a32, a48, a40);
        xrot< 2,8>(re, im, c[4], s[4], a32, a48, a40);
        xrot< 1,4>(re, im, c[5], s[5], a32, a48, a40);
        xrot<0,10>(re, im, c[6], s[6], a32, a48, a40);
        xrot<0, 5>(re, im, c[7], s[7], a32, a48, a40);
        xrot<48,2>(re, im, c[8], s[8], a32, a48, a40);
        xrot<24,1>(re, im, c[9], s[9], a32, a48, a40);
    }

    // ---- readout: Z-strings conjugated by R^3 ----
    // per-lane probs, then 16-point Walsh-Hadamard over reg index:
    float W[NR];
    #pragma unroll
    for (int r = 0; r < NR; ++r) W[r] = re[r] * re[r] + im[r] * im[r];
    #pragma unroll
    for (int bset = 0; bset < 4; ++bset) {
        const int bb = 1 << bset;
        #pragma unroll
        for (int r = 0; r < NR; ++r) {
            if (!(r & bb)) {
                const float u = W[r], v = W[r | bb];
                W[r] = u + v;  W[r | bb] = u - v;
            }
        }
    }
    // lane parity signs
    const float sg44 = (__builtin_popcount(lane & 44) & 1) ? -1.f : 1.f;
    const float sg26 = (__builtin_popcount(lane & 26) & 1) ? -1.f : 1.f;
    const float sg13 = (__builtin_popcount(lane & 13) & 1) ? -1.f : 1.f;
    const float sg38 = (__builtin_popcount(lane & 38) & 1) ? -1.f : 1.f;
    const float sg51 = (__builtin_popcount(lane & 51) & 1) ? -1.f : 1.f;
    const float sg25 = (__builtin_popcount(lane & 25) & 1) ? -1.f : 1.f;
    const float sg12 = (__builtin_popcount(lane & 12) & 1) ? -1.f : 1.f;

    float z[NQ];
    z[0] = sg44 * W[12];
    z[1] = sg26 * W[10];
    z[2] = sg13 * W[ 5];
    z[3] = sg38 * W[10];
    z[4] = sg51 * W[ 5];
    z[5] = sg25 * W[10];
    z[6] = sg12 * W[13];
    z[7] = sg38 * W[ 6];
    z[8] = sg51 * W[ 3];
    z[9] = sg25 * W[ 9];

    // cross-lane butterfly reduce
    #pragma unroll
    for (int q = 0; q < NQ; ++q) {
        z[q] += shufML< 1>(z[q], a32, a48, a40);
        z[q] += shufML< 2>(z[q], a32, a48, a40);
        z[q] += shufML< 4>(z[q], a32, a48, a40);
        z[q] += shufML< 8>(z[q], a32, a48, a40);
        z[q] += shufML<16>(z[q], a32, a48, a40);
        z[q] += shufML<32>(z[q], a32, a48, a40);
    }
    if (lane == 0) {
        #pragma unroll
        for (int q = 0; q < NQ; ++q) out[b * NQ + q] = z[q];
    }
}

extern "C" void kernel_launch(void* const* d_in, const int* in_sizes, int n_in,
                              void* d_out, int out_size, void* d_ws, size_t ws_size,
                              hipStream_t stream) {
    const float* x = (const float*)d_in[0];        // (BATCH, NQ) fp32
    const float* w = (const float*)d_in[1];        // (NDEPTH, NQ) fp32
    float* out = (float*)d_out;                    // (BATCH, NQ) fp32
    const int B = in_sizes[0] / NQ;
    vql_kernel<<<(B + 3) / 4, 256, 0, stream>>>(x, w, out, B);
}

// Round 13
// 11.443 us; speedup vs baseline: 1.7653x; 1.4574x over previous
//
#include <hip/hip_runtime.h>

#define NQ 10
#define NDEPTH 4
#define NR 16              // amplitudes per lane (2^4)

// One WAVE per batch element: 64 lanes x 16 complex amps = 1024 amplitudes.
// Flat index k = lane*16 + r; bit c of k: c>=4 -> lane bit (c-4), c<4 -> reg bit c.
// r13 FULL spectral restructuring:
//   After r12's Clifford conjugation the body = 30 commuting X-string
//   rotations = W^-1 . diag(e^{-i phi(k)}) . W  (W = unnormalized Walsh).
//   * W|psi_init> built DIRECTLY: psi_init = P_j (product state)  ->
//     W P_j psi = (W psi)(j^-T k), W(product) = product of f' = (f0 +- f1).
//     j^-T (from r7's verified j): bit c = k_0^..^k_c ^ k_9 (c<=8), bit9 = k_0^..^k_8.
//   * phi(k) per amp via 16-pt WHT of per-lane-signed coefficient array C[16]
//     (30 masks from r12, grouped by reg-part; lane-part gives the sign).
//   * W#2 = 10 butterfly levels (4 reg VALU + 6 lane: DPP 1/2/8, swizzle 4/16,
//     bpermute 32). Readout = r12's verified parity/Walsh readout verbatim.
//   1/1024 normalization folded into the init product.

__device__ __forceinline__ float xf(int i) { return __int_as_float(i); }
__device__ __forceinline__ int   fx(float f) { return __float_as_int(f); }

template<int M>
__device__ __forceinline__ float lane_xor(float v, int a32) {
    if constexpr (M == 1)        // quad_perm [1,0,3,2]
        return xf(__builtin_amdgcn_update_dpp(fx(v), fx(v), 0xB1, 0xF, 0xF, true));
    else if constexpr (M == 2)   // quad_perm [2,3,0,1]
        return xf(__builtin_amdgcn_update_dpp(fx(v), fx(v), 0x4E, 0xF, 0xF, true));
    else if constexpr (M == 8)   // row_ror:8
        return xf(__builtin_amdgcn_update_dpp(fx(v), fx(v), 0x128, 0xF, 0xF, true));
    else if constexpr (M == 4)   // ds_swizzle bit-mode xor 4
        return xf(__builtin_amdgcn_ds_swizzle(fx(v), 0x101F));
    else if constexpr (M == 16)  // ds_swizzle bit-mode xor 16
        return xf(__builtin_amdgcn_ds_swizzle(fx(v), 0x401F));
    else                         // M == 32: bpermute
        return xf(__builtin_amdgcn_ds_bpermute(a32, fx(v)));
}

__global__ __launch_bounds__(256, 2) void vql_kernel(
    const float* __restrict__ x,     // (B, NQ)
    const float* __restrict__ w,     // (NDEPTH, NQ)
    float* __restrict__ out,         // (B, NQ)
    int B)
{
    const int lane = threadIdx.x & 63;
    const int b = blockIdx.x * 4 + (threadIdx.x >> 6);
    if (b >= B) return;
    const int a32 = (lane ^ 32) << 2;

    // ---- per-batch angles (vectorized) ----
    const float2* xr = reinterpret_cast<const float2*>(x + b * NQ);
    const float2 x01 = xr[0], x23 = xr[1], x45 = xr[2], x67 = xr[3], x89 = xr[4];
    const float xa[NQ] = {0.5f * x01.x, 0.5f * x01.y, 0.5f * x23.x, 0.5f * x23.y,
                          0.5f * x45.x, 0.5f * x45.y, 0.5f * x67.x, 0.5f * x67.y,
                          0.5f * x89.x, 0.5f * x89.y};

    // ---- per-qubit Walsh factors of RX(w0q)RY(xq)|0>:  f'(t) = f(0) +- f(1) ----
    float F0r[NQ], F0i[NQ], F1r[NQ], F1i[NQ];
    #pragma unroll
    for (int q = 0; q < NQ; ++q) {
        float sy, cy, s, c;
        __sincosf(xa[q], &sy, &cy);
        __sincosf(0.5f * w[q], &s, &c);   // layer-0 weights
        const float v0r = c * cy,  v0i = -s * sy;
        const float v1r = c * sy,  v1i = -s * cy;
        F0r[q] = v0r + v1r;  F0i[q] = v0i + v1i;
        F1r[q] = v0r - v1r;  F1i[q] = v0i - v1i;
    }

    // ---- psi1 = W psi_init, built directly via j^-T bit formulas ----
    // qubit q bit of j^-T(k):  q0: rp4^PL4      q1: rp4^PL4^L5  q2: rp4^PL3^L5
    //   q3: rp4^PL2^L5  q4: rp4^PL1^L5  q5: rp4^L0^L5  q6: rp4^L5
    //   q7: rp3^L5      q8: rp2^L5      q9: rp1^L5
    // (rpN = XOR of low N reg bits, PLn = L0^..^Ln)
    const int L0 = lane & 1,        L1 = (lane >> 1) & 1, L2 = (lane >> 2) & 1;
    const int L3 = (lane >> 3) & 1, L4 = (lane >> 4) & 1, L5 = (lane >> 5) & 1;
    const int PL1 = L0 ^ L1, PL2 = PL1 ^ L2, PL3 = PL2 ^ L3, PL4 = PL3 ^ L4;
    const int g[7] = {PL4, PL4 ^ L5, PL3 ^ L5, PL2 ^ L5, PL1 ^ L5, L0 ^ L5, L5};
    #define SR_(q,bit) ((bit) ? F1r[q] : F0r[q])
    #define SI_(q,bit) ((bit) ? F1i[q] : F0i[q])

    float A_r[2], A_i[2];                 // prod q=0..6, for rp4 = 0/1
    #pragma unroll
    for (int t = 0; t < 2; ++t) {
        float ar = SR_(0, g[0] ^ t), ai = SI_(0, g[0] ^ t);
        #pragma unroll
        for (int q = 1; q < 7; ++q) {
            const float br = SR_(q, g[q] ^ t), bi = SI_(q, g[q] ^ t);
            const float nr = ar * br - ai * bi;
            const float ni = ar * bi + ai * br;
            ar = nr; ai = ni;
        }
        A_r[t] = ar * (1.0f / 1024.0f);   // fold W^-1 normalization
        A_i[t] = ai * (1.0f / 1024.0f);
    }
    // u7/u8/u9: f'_{7,8,9}(t ^ L5)
    float Gr[2][2], Gi[2][2];             // u8[t2]*u9[t1]
    #pragma unroll
    for (int t2 = 0; t2 < 2; ++t2)
        #pragma unroll
        for (int t1 = 0; t1 < 2; ++t1) {
            const float ar = SR_(8, t2 ^ L5), ai = SI_(8, t2 ^ L5);
            const float br = SR_(9, t1 ^ L5), bi = SI_(9, t1 ^ L5);
            Gr[t2][t1] = ar * br - ai * bi;
            Gi[t2][t1] = ar * bi + ai * br;
        }
    float Br_[2][2][2], Bi_[2][2][2];     // u7[t3]*G[t2][t1]
    #pragma unroll
    for (int t3 = 0; t3 < 2; ++t3)
        #pragma unroll
        for (int t2 = 0; t2 < 2; ++t2)
            #pragma unroll
            for (int t1 = 0; t1 < 2; ++t1) {
                const float ar = SR_(7, t3 ^ L5), ai = SI_(7, t3 ^ L5);
                Br_[t3][t2][t1] = ar * Gr[t2][t1] - ai * Gi[t2][t1];
                Bi_[t3][t2][t1] = ar * Gi[t2][t1] + ai * Gr[t2][t1];
            }
    float re[NR], im[NR];
    #pragma unroll
    for (int r = 0; r < NR; ++r) {
        const int r0 = r & 1, r1 = (r >> 1) & 1, r2 = (r >> 2) & 1, r3 = (r >> 3) & 1;
        const int p1 = r0, p2 = r0 ^ r1, p3 = p2 ^ r2, p4 = p3 ^ r3;
        const float br = Br_[p3][p2][p1], bi = Bi_[p3][p2][p1];
        re[r] = A_r[p4] * br - A_i[p4] * bi;
        im[r] = A_r[p4] * bi + A_i[p4] * br;
    }
    #undef SR_
    #undef SI_

    // ---- diagonal phases: phi[r] = sum_m C[m] (-1)^{pc(r&m)} ----
    // Masks (ML,MR) from r12 (verified): grouped by MR; lane part -> sign.
    float h1[NQ], h2[NQ], h3[NQ];
    #pragma unroll
    for (int q = 0; q < NQ; ++q) {
        h1[q] = 0.5f * w[NQ + q];
        h2[q] = 0.5f * w[2 * NQ + q];
        h3[q] = 0.5f * w[3 * NQ + q];
    }
    #define SG_(M) ((__builtin_popcount(lane & (M)) & 1) ? -1.f : 1.f)
    const float s1 = SG_(1),  s2 = SG_(2),  s3 = SG_(3),  s4 = SG_(4),  s5 = SG_(5);
    const float s6 = SG_(6),  s8 = SG_(8),  s10 = SG_(10), s12 = SG_(12);
    const float s16 = SG_(16), s20 = SG_(20), s24 = SG_(24), s32 = SG_(32);
    const float s40 = SG_(40), s48 = SG_(48);
    #undef SG_

    float C[NR];
    C[0]  = s32 * h1[0] + s16 * h1[1] + s8 * h1[2] + s4 * h1[3] + s2 * h1[4] + s1 * h1[5]
          + s48 * h2[0] + s24 * h2[1] + s12 * h2[2] + s6 * h2[3] + s3 * h2[4]
          + s40 * h3[0] + s20 * h3[1] + s10 * h3[2] + s5 * h3[3];
    C[8]  = h1[6] + s1 * h2[5] + s2 * h3[4];
    C[4]  = h1[7] + s1 * h3[5];
    C[2]  = h1[8] + s48 * h3[8];
    C[1]  = h1[9] + s48 * h2[9] + s24 * h3[9];
    C[12] = h2[6];
    C[6]  = h2[7];
    C[3]  = h2[8];
    C[10] = h3[6];
    C[5]  = h3[7];
    C[7] = 0.f; C[9] = 0.f; C[11] = 0.f; C[13] = 0.f; C[14] = 0.f; C[15] = 0.f;

    #pragma unroll
    for (int bset = 0; bset < 4; ++bset) {      // 16-pt WHT: C -> phi
        const int bb = 1 << bset;
        #pragma unroll
        for (int r = 0; r < NR; ++r) {
            if (!(r & bb)) {
                const float u = C[r], v = C[r | bb];
                C[r] = u + v;  C[r | bb] = u - v;
            }
        }
    }
    // apply e^{-i phi}: re' = re*c + im*s ; im' = im*c - re*s
    #pragma unroll
    for (int r = 0; r < NR; ++r) {
        float sp, cp;
        __sincosf(C[r], &sp, &cp);
        const float nr = re[r] * cp + im[r] * sp;
        const float ni = im[r] * cp - re[r] * sp;
        re[r] = nr; im[r] = ni;
    }

    // ---- W#2: full 10-level Walsh butterfly ----
    #pragma unroll
    for (int bset = 0; bset < 4; ++bset) {      // reg levels (VALU only)
        const int bb = 1 << bset;
        #pragma unroll
        for (int r = 0; r < NR; ++r) {
            if (!(r & bb)) {
                float u = re[r], v = re[r | bb];
                re[r] = u + v;  re[r | bb] = u - v;
                u = im[r]; v = im[r | bb];
                im[r] = u + v;  im[r | bb] = u - v;
            }
        }
    }
    // lane levels: v' = sgn*v + partner
    {
        const float sgA = (lane &  1) ? -1.f : 1.f;
        const float sgB = (lane &  2) ? -1.f : 1.f;
        const float sgC = (lane &  4) ? -1.f : 1.f;
        const float sgD = (lane &  8) ? -1.f : 1.f;
        const float sgE = (lane & 16) ? -1.f : 1.f;
        const float sgF = (lane & 32) ? -1.f : 1.f;
        #pragma unroll
        for (int r = 0; r < NR; ++r) {
            float p;
            p = lane_xor< 1>(re[r], a32); re[r] = fmaf(sgA, re[r], p);
            p = lane_xor< 1>(im[r], a32); im[r] = fmaf(sgA, im[r], p);
            p = lane_xor< 2>(re[r], a32); re[r] = fmaf(sgB, re[r], p);
            p = lane_xor< 2>(im[r], a32); im[r] = fmaf(sgB, im[r], p);
            p = lane_xor< 4>(re[r], a32); re[r] = fmaf(sgC, re[r], p);
            p = lane_xor< 4>(im[r], a32); im[r] = fmaf(sgC, im[r], p);
            p = lane_xor< 8>(re[r], a32); re[r] = fmaf(sgD, re[r], p);
            p = lane_xor< 8>(im[r], a32); im[r] = fmaf(sgD, im[r], p);
            p = lane_xor<16>(re[r], a32); re[r] = fmaf(sgE, re[r], p);
            p = lane_xor<16>(im[r], a32); im[r] = fmaf(sgE, im[r], p);
            p = lane_xor<32>(re[r], a32); re[r] = fmaf(sgF, re[r], p);
            p = lane_xor<32>(im[r], a32); im[r] = fmaf(sgF, im[r], p);
        }
    }

    // ---- readout (r12 verbatim): parity-mask observables ----
    float W[NR];
    #pragma unroll
    for (int r = 0; r < NR; ++r) W[r] = re[r] * re[r] + im[r] * im[r];
    #pragma unroll
    for (int bset = 0; bset < 4; ++bset) {
        const int bb = 1 << bset;
        #pragma unroll
        for (int r = 0; r < NR; ++r) {
            if (!(r & bb)) {
                const float u = W[r], v = W[r | bb];
                W[r] = u + v;  W[r | bb] = u - v;
            }
        }
    }
    const float sg44 = (__builtin_popcount(lane & 44) & 1) ? -1.f : 1.f;
    const float sg26 = (__builtin_popcount(lane & 26) & 1) ? -1.f : 1.f;
    const float sg13 = (__builtin_popcount(lane & 13) & 1) ? -1.f : 1.f;
    const float sg38 = (__builtin_popcount(lane & 38) & 1) ? -1.f : 1.f;
    const float sg51 = (__builtin_popcount(lane & 51) & 1) ? -1.f : 1.f;
    const float sg25 = (__builtin_popcount(lane & 25) & 1) ? -1.f : 1.f;
    const float sg12 = (__builtin_popcount(lane & 12) & 1) ? -1.f : 1.f;

    float z[NQ];
    z[0] = sg44 * W[12];
    z[1] = sg26 * W[10];
    z[2] = sg13 * W[ 5];
    z[3] = sg38 * W[10];
    z[4] = sg51 * W[ 5];
    z[5] = sg25 * W[10];
    z[6] = sg12 * W[13];
    z[7] = sg38 * W[ 6];
    z[8] = sg51 * W[ 3];
    z[9] = sg25 * W[ 9];

    #pragma unroll
    for (int q = 0; q < NQ; ++q) {
        z[q] += lane_xor< 1>(z[q], a32);
        z[q] += lane_xor< 2>(z[q], a32);
        z[q] += lane_xor< 4>(z[q], a32);
        z[q] += lane_xor< 8>(z[q], a32);
        z[q] += lane_xor<16>(z[q], a32);
        z[q] += lane_xor<32>(z[q], a32);
    }
    if (lane == 0) {
        #pragma unroll
        for (int q = 0; q < NQ; ++q) out[b * NQ + q] = z[q];
    }
}

extern "C" void kernel_launch(void* const* d_in, const int* in_sizes, int n_in,
                              void* d_out, int out_size, void* d_ws, size_t ws_size,
                              hipStream_t stream) {
    const float* x = (const float*)d_in[0];        // (BATCH, NQ) fp32
    const float* w = (const float*)d_in[1];        // (NDEPTH, NQ) fp32
    float* out = (float*)d_out;                    // (BATCH, NQ) fp32
    const int B = in_sizes[0] / NQ;
    vql_kernel<<<(B + 3) / 4, 256, 0, stream>>>(x, w, out, B);
}